// Round 7
// baseline (76.511 us; speedup 1.0000x reference)
//
#include <hip/hip_runtime.h>
#include <math.h>

#define NB 8
#define NN 2048
#define NTHREADS 512
#define SPLIT 32
#define RPT 4
#define ROWS_PER_BLOCK 64          // (NTHREADS/SPLIT) * RPT = 16*4
#define LOG2E 1.44269504088896340736f

// Native exp2 (bare v_exp_f32) when available; guard makes this
// incapable of failing to compile — falls back to libm exp2f.
#if defined(__has_builtin)
#  if __has_builtin(__builtin_amdgcn_exp2f)
#    define EXP2F(x) __builtin_amdgcn_exp2f(x)
#  else
#    define EXP2F(x) exp2f(x)
#  endif
#else
#  define EXP2F(x) exp2f(x)
#endif

// Fused Fano-octonion attention, V-only LDS formulation.
// s(n,m) = qa(n) . v(m)  with qa = A^T (w ⊙ A v(n)),  A = Fano incidence
// (7x7, each point on 3 lines). The K matrix is never formed.
// Whole batch's V staged once in LDS: 3 transposed float2 planes + 1 scalar
// plane (56 KiB total, below the 64 KiB static-shared boundary). All reads
// are <=2-way bank-aliased at the 32-lane split (free on CDNA4).
// Each thread: 4 query rows, m-loop split 32 ways, butterfly merge,
// L2-normalized epilogue.
__global__ __launch_bounds__(NTHREADS, 2)
void fano_attn_kernel(const float* __restrict__ o,
                      const float* __restrict__ lw,
                      float* __restrict__ out) {
    // plane p in 0..2, row m: (imag[2p], imag[2p+1]); sV3[m] = imag[6]
    __shared__ float sV[3][NN][2];   // 48 KiB
    __shared__ float sV3[NN];        //  8 KiB

    const int tid = threadIdx.x;
    const int t   = tid & (SPLIT - 1);   // split lane 0..31
    const int g   = tid >> 5;            // query group 0..15
    const int b   = blockIdx.x >> 5;     // batch (32 blocks per batch)
    const int rowbase = (blockIdx.x & 31) * ROWS_PER_BLOCK;
    const float* obatch = o + (size_t)b * (NN * 8);

    // ---- w = softmax(line_weights)/7 * log2(e)  (uniform across block) ----
    float w[7];
    {
        float e[7]; float se = 0.f;
#pragma unroll
        for (int l = 0; l < 7; ++l) { e[l] = __expf(lw[l]); se += e[l]; }
        const float inv = LOG2E / (7.0f * se);
#pragma unroll
        for (int l = 0; l < 7; ++l) w[l] = e[l] * inv;
    }

    // ---- q-row global loads (issued before staging to overlap latency) ----
    float4 qr0[RPT], qr1[RPT];
#pragma unroll
    for (int k = 0; k < RPT; ++k) {
        const float* row = obatch + (size_t)(rowbase + g * RPT + k) * 8;
        qr0[k] = *(const float4*)row;
        qr1[k] = *(const float4*)(row + 4);
    }

    // ---- stage whole batch V into LDS planes (coalesced, <=2-way writes) ----
#pragma unroll
    for (int j = 0; j < NN / NTHREADS; ++j) {
        const int m = tid + j * NTHREADS;
        const float* row = obatch + (size_t)m * 8;
        const float4 a0 = *(const float4*)row;
        const float4 a1 = *(const float4*)(row + 4);
        *(float2*)&sV[0][m][0] = make_float2(a0.y, a0.z);
        *(float2*)&sV[1][m][0] = make_float2(a0.w, a1.x);
        *(float2*)&sV[2][m][0] = make_float2(a1.y, a1.z);
        sV3[m] = a1.w;
    }

    // ---- per-row qa = A^T (w ⊙ A v) ----
    float qa[RPT][7], realp[RPT];
#pragma unroll
    for (int k = 0; k < RPT; ++k) {
        realp[k] = qr0[k].x;
        const float i0 = qr0[k].y, i1 = qr0[k].z, i2 = qr0[k].w;
        const float i3 = qr1[k].x, i4 = qr1[k].y, i5 = qr1[k].z, i6 = qr1[k].w;
        const float q0 = (i0 + i1 + i2) * w[0];
        const float q1 = (i0 + i3 + i4) * w[1];
        const float q2 = (i0 + i5 + i6) * w[2];
        const float q3 = (i1 + i3 + i5) * w[3];
        const float q4 = (i1 + i4 + i6) * w[4];
        const float q5 = (i2 + i3 + i6) * w[5];
        const float q6 = (i2 + i4 + i5) * w[6];
        qa[k][0] = q0 + q1 + q2;
        qa[k][1] = q0 + q3 + q4;
        qa[k][2] = q0 + q5 + q6;
        qa[k][3] = q1 + q3 + q5;
        qa[k][4] = q1 + q4 + q6;
        qa[k][5] = q2 + q3 + q6;
        qa[k][6] = q2 + q4 + q5;
    }

    float acc[RPT][7];
    float psum[RPT];
#pragma unroll
    for (int k = 0; k < RPT; ++k) {
        psum[k] = 0.f;
#pragma unroll
        for (int d = 0; d < 7; ++d) acc[k][d] = 0.f;
    }

    __syncthreads();

    // ---- main loop: 64 iters, 1 V-row read serves 4 query rows ----
#pragma unroll 4
    for (int i = 0; i < NN / SPLIT; ++i) {
        const int m = i * SPLIT + t;
        const float2 va = *(const float2*)&sV[0][m][0];
        const float2 vb = *(const float2*)&sV[1][m][0];
        const float2 vc = *(const float2*)&sV[2][m][0];
        const float  vd = sV3[m];
#pragma unroll
        for (int k = 0; k < RPT; ++k) {
            float s = qa[k][0] * va.x;
            s = fmaf(qa[k][1], va.y, s);
            s = fmaf(qa[k][2], vb.x, s);
            s = fmaf(qa[k][3], vb.y, s);
            s = fmaf(qa[k][4], vc.x, s);
            s = fmaf(qa[k][5], vc.y, s);
            s = fmaf(qa[k][6], vd,   s);
            const float p = EXP2F(s);   // e^s exactly (log2e folded into qa)
            psum[k] += p;
            acc[k][0] = fmaf(p, va.x, acc[k][0]);
            acc[k][1] = fmaf(p, va.y, acc[k][1]);
            acc[k][2] = fmaf(p, vb.x, acc[k][2]);
            acc[k][3] = fmaf(p, vb.y, acc[k][3]);
            acc[k][4] = fmaf(p, vc.x, acc[k][4]);
            acc[k][5] = fmaf(p, vc.y, acc[k][5]);
            acc[k][6] = fmaf(p, vd,   acc[k][6]);
        }
    }

    // ---- butterfly merge over the 32 split lanes ----
#pragma unroll
    for (int ofs = 1; ofs < SPLIT; ofs <<= 1) {
#pragma unroll
        for (int k = 0; k < RPT; ++k) {
            psum[k] += __shfl_xor(psum[k], ofs);
#pragma unroll
            for (int d = 0; d < 7; ++d)
                acc[k][d] += __shfl_xor(acc[k][d], ofs);
        }
    }

    // ---- epilogue: normalize + store (one writer per group) ----
    if (t == 0) {
#pragma unroll
        for (int k = 0; k < RPT; ++k) {
            const float invs = 1.0f / psum[k];
            float oi[7];
            float n2 = realp[k] * realp[k];
#pragma unroll
            for (int d = 0; d < 7; ++d) {
                oi[d] = acc[k][d] * invs;
                n2 += oi[d] * oi[d];
            }
            const float scale = 1.0f / (sqrtf(n2) + 1e-15f);
            float4 r0, r1;
            r0.x = realp[k] * scale; r0.y = oi[0] * scale;
            r0.z = oi[1] * scale;    r0.w = oi[2] * scale;
            r1.x = oi[3] * scale;    r1.y = oi[4] * scale;
            r1.z = oi[5] * scale;    r1.w = oi[6] * scale;
            float* orow = out + ((size_t)(b * NN + rowbase + g * RPT + k)) * 8;
            *(float4*)orow       = r0;
            *(float4*)(orow + 4) = r1;
        }
    }
}

extern "C" void kernel_launch(void* const* d_in, const int* in_sizes, int n_in,
                              void* d_out, int out_size, void* d_ws, size_t ws_size,
                              hipStream_t stream) {
    const float* o  = (const float*)d_in[0];
    const float* lw = (const float*)d_in[1];
    float* out      = (float*)d_out;
    const int grid = NB * (NN / ROWS_PER_BLOCK);   // 8 * 32 = 256 blocks
    fano_attn_kernel<<<dim3(grid), dim3(NTHREADS), 0, stream>>>(o, lw, out);
}

// Round 9
// 75.661 us; speedup vs baseline: 1.0112x; 1.0112x over previous
//
#include <hip/hip_runtime.h>
#include <math.h>

#define NB 8
#define NN 2048
#define NTHREADS 512
#define SPLIT 64
#define RPT 4
#define ROWS_PER_BLOCK ((NTHREADS / SPLIT) * RPT)      // 8 groups * 4 = 32
#define BLOCKS_PER_BATCH (NN / ROWS_PER_BLOCK)         // 64
#define LOG2E 1.44269504088896340736f

typedef float v2f __attribute__((ext_vector_type(2)));

// Native exp2 (bare v_exp_f32) when available; guarded fallback.
#if defined(__has_builtin)
#  if __has_builtin(__builtin_amdgcn_exp2f)
#    define EXP2F(x) __builtin_amdgcn_exp2f(x)
#  else
#    define EXP2F(x) exp2f(x)
#  endif
#else
#  define EXP2F(x) exp2f(x)
#endif

// Fused Fano-octonion attention, V-only LDS formulation.
// s(n,m) = qa(n) . v(m),  qa = A^T (w ⊙ A v(n)),  A = Fano incidence.
// R7 changes vs R6 (76.5 us, kernel latency-bound at 2 waves/SIMD):
//  - SPLIT 32->64: grid 256->512 blocks = 2 blocks/CU = 4 waves/SIMD
//    (LDS bytes/pair unchanged; 2x latency hiding).
//  - packed-f32 math (v_pk_fma_f32 via ext_vector float2): ~11 instead of
//    15 VALU instrs per (n,m) pair.
__global__ __launch_bounds__(NTHREADS, 4)
void fano_attn_kernel(const float* __restrict__ o,
                      const float* __restrict__ lw,
                      float* __restrict__ out) {
    // plane p in 0..2, row m: (imag[2p], imag[2p+1]); sV3[m] = imag[6]
    __shared__ float sV[3][NN][2];   // 48 KiB
    __shared__ float sV3[NN];        //  8 KiB  (56 KiB total; 2 blocks/CU fit)

    const int tid = threadIdx.x;
    const int t   = tid % SPLIT;             // split lane 0..63 (= lane in wave)
    const int g   = tid / SPLIT;             // query group = wave 0..7
    const int b   = blockIdx.x / BLOCKS_PER_BATCH;
    const int rowbase = (blockIdx.x % BLOCKS_PER_BATCH) * ROWS_PER_BLOCK;
    const float* obatch = o + (size_t)b * (NN * 8);

    // ---- w = softmax(line_weights)/7 * log2(e)  (uniform across block) ----
    float w[7];
    {
        float e[7]; float se = 0.f;
#pragma unroll
        for (int l = 0; l < 7; ++l) { e[l] = __expf(lw[l]); se += e[l]; }
        const float inv = LOG2E / (7.0f * se);
#pragma unroll
        for (int l = 0; l < 7; ++l) w[l] = e[l] * inv;
    }

    // ---- q-row global loads (issued early to overlap staging latency) ----
    float4 qr0[RPT], qr1[RPT];
#pragma unroll
    for (int k = 0; k < RPT; ++k) {
        const float* row = obatch + (size_t)(rowbase + g * RPT + k) * 8;
        qr0[k] = *(const float4*)row;
        qr1[k] = *(const float4*)(row + 4);
    }

    // ---- stage whole batch V into LDS planes ----
#pragma unroll
    for (int j = 0; j < NN / NTHREADS; ++j) {
        const int m = tid + j * NTHREADS;
        const float* row = obatch + (size_t)m * 8;
        const float4 a0 = *(const float4*)row;
        const float4 a1 = *(const float4*)(row + 4);
        *(float2*)&sV[0][m][0] = make_float2(a0.y, a0.z);
        *(float2*)&sV[1][m][0] = make_float2(a0.w, a1.x);
        *(float2*)&sV[2][m][0] = make_float2(a1.y, a1.z);
        sV3[m] = a1.w;
    }

    // ---- per-row qa = A^T (w ⊙ A v), packed as 3x float2 + 1 scalar ----
    v2f qa01[RPT], qa23[RPT], qa45[RPT];
    float qa6[RPT], realp[RPT];
#pragma unroll
    for (int k = 0; k < RPT; ++k) {
        realp[k] = qr0[k].x;
        const float i0 = qr0[k].y, i1 = qr0[k].z, i2 = qr0[k].w;
        const float i3 = qr1[k].x, i4 = qr1[k].y, i5 = qr1[k].z, i6 = qr1[k].w;
        const float q0 = (i0 + i1 + i2) * w[0];
        const float q1 = (i0 + i3 + i4) * w[1];
        const float q2 = (i0 + i5 + i6) * w[2];
        const float q3 = (i1 + i3 + i5) * w[3];
        const float q4 = (i1 + i4 + i6) * w[4];
        const float q5 = (i2 + i3 + i6) * w[5];
        const float q6 = (i2 + i4 + i5) * w[6];
        qa01[k] = (v2f){q0 + q1 + q2, q0 + q3 + q4};
        qa23[k] = (v2f){q0 + q5 + q6, q1 + q3 + q5};
        qa45[k] = (v2f){q1 + q4 + q6, q2 + q3 + q6};
        qa6[k]  = q2 + q4 + q5;
    }

    v2f accv[RPT][3];
    float acc6[RPT], psum[RPT];
#pragma unroll
    for (int k = 0; k < RPT; ++k) {
        psum[k] = 0.f; acc6[k] = 0.f;
#pragma unroll
        for (int j = 0; j < 3; ++j) accv[k][j] = (v2f){0.f, 0.f};
    }

    __syncthreads();

    // ---- main loop: 32 iters, 1 V-row read serves 4 query rows ----
#pragma unroll 4
    for (int i = 0; i < NN / SPLIT; ++i) {
        const int m = i * SPLIT + t;
        const v2f  va = *(const v2f*)&sV[0][m][0];
        const v2f  vb = *(const v2f*)&sV[1][m][0];
        const v2f  vc = *(const v2f*)&sV[2][m][0];
        const float vd = sV3[m];
#pragma unroll
        for (int k = 0; k < RPT; ++k) {
            // dot7: pk_mul + 2 pk_fma + hadd + fma  (contract=fast)
            const v2f d = qa01[k] * va + qa23[k] * vb + qa45[k] * vc;
            const float s = fmaf(qa6[k], vd, d.x + d.y);
            const float p = EXP2F(s);      // e^s exactly (log2e folded into qa)
            psum[k] += p;
            const v2f p2 = (v2f){p, p};
            accv[k][0] = p2 * va + accv[k][0];   // pk_fma x3
            accv[k][1] = p2 * vb + accv[k][1];
            accv[k][2] = p2 * vc + accv[k][2];
            acc6[k] = fmaf(p, vd, acc6[k]);
        }
    }

    // ---- butterfly merge over the 64 split lanes (full wave) ----
#pragma unroll
    for (int ofs = 1; ofs < SPLIT; ofs <<= 1) {
#pragma unroll
        for (int k = 0; k < RPT; ++k) {
            psum[k] += __shfl_xor(psum[k], ofs);
#pragma unroll
            for (int j = 0; j < 3; ++j) {
                accv[k][j].x += __shfl_xor(accv[k][j].x, ofs);
                accv[k][j].y += __shfl_xor(accv[k][j].y, ofs);
            }
            acc6[k] += __shfl_xor(acc6[k], ofs);
        }
    }

    // ---- epilogue: normalize + store (one writer per wave) ----
    if (t == 0) {
#pragma unroll
        for (int k = 0; k < RPT; ++k) {
            const float invs = 1.0f / psum[k];
            float oi[7] = { accv[k][0].x, accv[k][0].y, accv[k][1].x,
                            accv[k][1].y, accv[k][2].x, accv[k][2].y, acc6[k] };
            float n2 = realp[k] * realp[k];
#pragma unroll
            for (int d = 0; d < 7; ++d) {
                oi[d] *= invs;
                n2 = fmaf(oi[d], oi[d], n2);
            }
            const float scale = 1.0f / (sqrtf(n2) + 1e-15f);
            float4 r0, r1;
            r0.x = realp[k] * scale; r0.y = oi[0] * scale;
            r0.z = oi[1] * scale;    r0.w = oi[2] * scale;
            r1.x = oi[3] * scale;    r1.y = oi[4] * scale;
            r1.z = oi[5] * scale;    r1.w = oi[6] * scale;
            float* orow = out + ((size_t)(b * NN + rowbase + g * RPT + k)) * 8;
            *(float4*)orow       = r0;
            *(float4*)(orow + 4) = r1;
        }
    }
}

extern "C" void kernel_launch(void* const* d_in, const int* in_sizes, int n_in,
                              void* d_out, int out_size, void* d_ws, size_t ws_size,
                              hipStream_t stream) {
    const float* o  = (const float*)d_in[0];
    const float* lw = (const float*)d_in[1];
    float* out      = (float*)d_out;
    const int grid = NB * BLOCKS_PER_BATCH;   // 8 * 64 = 512 blocks, 2/CU
    fano_attn_kernel<<<dim3(grid), dim3(NTHREADS), 0, stream>>>(o, lw, out);
}